// Round 1
// 1651.445 us; speedup vs baseline: 1.2551x; 1.2551x over previous
//
#include <hip/hip_runtime.h>
#include <stdint.h>
#include <stddef.h>

// y[m][n] = (sum_k x[m][k] * w[k][n]) * scale[n] + bias[n]
// M = 8192 (B*S), K = 4096 (DIN), N = 16384 (NF)

#define M_DIM 8192
#define K_DIM 4096
#define N_DIM 16384

typedef unsigned short u16;
typedef __attribute__((ext_vector_type(8))) short  short8;   // 8 x bf16 (MFMA A/B frag)
typedef __attribute__((ext_vector_type(8))) u16    ushort8;
typedef __attribute__((ext_vector_type(4))) float  floatx4;  // MFMA C/D frag

__device__ __forceinline__ u16 f2bf_rne(float f) {
    unsigned u = __float_as_uint(f);
    return (u16)((u + 0x7fffu + ((u >> 16) & 1u)) >> 16);
}

// ---------------------------------------------------------------------------
// Kernel 1: x fp32 [8192][4096] -> bf16 same layout (unchanged; ~32 us).
// ---------------------------------------------------------------------------
__global__ __launch_bounds__(256) void cvt_x_bf16(const float* __restrict__ x,
                                                  u16* __restrict__ xb) {
    size_t e = ((size_t)blockIdx.x * 256 + threadIdx.x) * 8;
    floatx4 a = *(const floatx4*)(x + e);
    floatx4 b = *(const floatx4*)(x + e + 4);
    ushort8 o;
    o[0] = f2bf_rne(a[0]); o[1] = f2bf_rne(a[1]);
    o[2] = f2bf_rne(a[2]); o[3] = f2bf_rne(a[3]);
    o[4] = f2bf_rne(b[0]); o[5] = f2bf_rne(b[1]);
    o[6] = f2bf_rne(b[2]); o[7] = f2bf_rne(b[3]);
    *(ushort8*)(xb + e) = o;
}

// ---------------------------------------------------------------------------
// Kernel 2 (REWRITTEN): weight int32 [K][N] -> bf16 Wt [N][K], LDS-tiled.
// Old version stored 16 B/lane scattered at 8 KB stride (partial-line HBM
// writes). New: tile 64(n) x 256(k); loads 256 B-coalesced rows; LDS with
// XOR swizzle (kc ^= n&7) so both ds_write_b128 and ds_read_b128 spread
// across bank-quads; stores are 64 B-contiguous full lines.
// Grid: (N/64, K/256) = (256, 16), 256 threads.
// ---------------------------------------------------------------------------
__global__ __launch_bounds__(256) void cvt_w_t(const int* __restrict__ w,
                                               u16* __restrict__ wt) {
    __shared__ u16 lt[64 * 256];   // 32 KiB: [n_local][k_local]
    const int t  = threadIdx.x;
    const int n0 = blockIdx.x * 64;
    const int k0 = blockIdx.y * 256;
    {
        const int nl = t & 63, kg = t >> 6;          // lane n, wave k-group
        const int nsw = (nl & 7) * 8;
#pragma unroll
        for (int c = 0; c < 8; ++c) {
            const int kc = kg + c * 4;               // k-chunk 0..31
            ushort8 o;
#pragma unroll
            for (int u = 0; u < 8; ++u) {
                // wave reads 64 consecutive ints (256 B) per (kc,u)
                float f = (float)w[(size_t)(k0 + kc * 8 + u) * N_DIM + n0 + nl];
                o[u] = (u16)(__float_as_uint(f) >> 16);   // exact for |v| <= 128
            }
            *(ushort8*)(lt + nl * 256 + ((kc * 8) ^ nsw)) = o;
        }
    }
    __syncthreads();
    {
        const int nl = t >> 2, kq = t & 3;
        const int nsw = (nl & 7) * 8;
        u16* orow = wt + (size_t)(n0 + nl) * K_DIM + k0;
#pragma unroll
        for (int c = 0; c < 8; ++c) {
            const int kc = kq + c * 4;
            ushort8 v = *(const ushort8*)(lt + nl * 256 + ((kc * 8) ^ nsw));
            *(ushort8*)(orow + kc * 8) = v;          // 4 lanes = 64 B contiguous
        }
    }
}

// ---------------------------------------------------------------------------
// Kernel 3 (REWRITTEN): 256x256-tile 8-phase bf16 GEMM (guide §5 template).
//   BM=BN=256, BK=64, 512 threads = 8 waves (2M x 4N), per-wave 128x64 out.
//   LDS 128 KiB = 2 K-tile buffers x 64 KiB; staged at 16 KiB piece
//   granularity, 1 piece per phase, counted vmcnt(6) (T3+T4). Pieces per
//   K-tile, in consumption-retire order:
//     B-h0 (Wt rows 0..127)   -- read fully in phase 1 (bf held in regs)
//     B-h1 (rows 128..255)    -- read fully in phase 1
//     A-q01 (m-quadrants 0,1) -- read phases 1,2
//     A-q23 (m-quadrants 2,3) -- read phases 3,4
//   During tile t's phases we stage: P1: A-q23(t+1) -> other buf;
//   P2/P3/P4: B-h0/B-h1/A-q01(t+2) -> CURRENT buf (regions already retired,
//   issue is behind the retiring phase's trailing barrier -> race-free).
//   vmcnt(6) at P4 completes everything except the last 3 pieces => tile t+1
//   fully resident. LDS XOR-swizzle (T2): linear global_load_lds dest,
//   k-chunk of the GLOBAL source pre-permuted by (row&7); reads XOR the same
//   (rule #21). setprio(1) around each 16-MFMA cluster (T5). Bijective XCD
//   swizzle on the 2048-block grid (T1).
//   A-row order in LDS: lds_row = q*64 + mg*32 + r5  (m = mg*128+q*32+r5)
//   so each phase's A-quadrant is one contiguous 8 KiB half-piece.
// Epilogue: out = acc * scale[n] + bias[n], fp32. K-ascending MFMA order ==
// previous kernel => bitwise-identical result.
// ---------------------------------------------------------------------------
__device__ __forceinline__ void gload16(u16* dst, const u16* src) {
    __builtin_amdgcn_global_load_lds(
        (const __attribute__((address_space(1))) void*)src,
        (__attribute__((address_space(3))) void*)dst,
        16, 0, 0);
}

#define MFMA16 __builtin_amdgcn_mfma_f32_16x16x32_bf16
#define SCHED0() __builtin_amdgcn_sched_barrier(0)
#define BAR() do { asm volatile("" ::: "memory"); SCHED0();                  \
                   __builtin_amdgcn_s_barrier();                             \
                   SCHED0(); asm volatile("" ::: "memory"); } while (0)
#define VMCNT(n) asm volatile("s_waitcnt vmcnt(" #n ")" ::: "memory")

#define KPH_MFMA(P)                                                          \
    __builtin_amdgcn_s_setprio(1);                                           \
    acc[2*(P)  ][0] = MFMA16(af0, bf[0][0], acc[2*(P)  ][0], 0, 0, 0);       \
    acc[2*(P)  ][1] = MFMA16(af0, bf[1][0], acc[2*(P)  ][1], 0, 0, 0);       \
    acc[2*(P)  ][2] = MFMA16(af0, bf[2][0], acc[2*(P)  ][2], 0, 0, 0);       \
    acc[2*(P)  ][3] = MFMA16(af0, bf[3][0], acc[2*(P)  ][3], 0, 0, 0);       \
    acc[2*(P)+1][0] = MFMA16(af2, bf[0][0], acc[2*(P)+1][0], 0, 0, 0);       \
    acc[2*(P)+1][1] = MFMA16(af2, bf[1][0], acc[2*(P)+1][1], 0, 0, 0);       \
    acc[2*(P)+1][2] = MFMA16(af2, bf[2][0], acc[2*(P)+1][2], 0, 0, 0);       \
    acc[2*(P)+1][3] = MFMA16(af2, bf[3][0], acc[2*(P)+1][3], 0, 0, 0);       \
    acc[2*(P)  ][0] = MFMA16(af1, bf[0][1], acc[2*(P)  ][0], 0, 0, 0);       \
    acc[2*(P)  ][1] = MFMA16(af1, bf[1][1], acc[2*(P)  ][1], 0, 0, 0);       \
    acc[2*(P)  ][2] = MFMA16(af1, bf[2][1], acc[2*(P)  ][2], 0, 0, 0);       \
    acc[2*(P)  ][3] = MFMA16(af1, bf[3][1], acc[2*(P)  ][3], 0, 0, 0);       \
    acc[2*(P)+1][0] = MFMA16(af3, bf[0][1], acc[2*(P)+1][0], 0, 0, 0);       \
    acc[2*(P)+1][1] = MFMA16(af3, bf[1][1], acc[2*(P)+1][1], 0, 0, 0);       \
    acc[2*(P)+1][2] = MFMA16(af3, bf[2][1], acc[2*(P)+1][2], 0, 0, 0);       \
    acc[2*(P)+1][3] = MFMA16(af3, bf[3][1], acc[2*(P)+1][3], 0, 0, 0);       \
    __builtin_amdgcn_s_setprio(0);

// One K-tile (4 phases). S1: stage A-q23(kt+1); S2: stage 3 pieces of kt+2;
// VMN: vmcnt immediate at phase 4 (6 steady-state, 0 at the tail).
#define KTILE(S1, S2, VMN)                                                   \
  {                                                                          \
    const u16* Lb = lds + cur * 32768;                                       \
    u16* Sb = lds + (cur ^ 1) * 32768;                                       \
    u16* Cb = lds + cur * 32768;                                             \
    const int kadv1 = (kt + 1) * 64;                                         \
    const int kadv2 = (kt + 2) * 64;                                         \
    /* ---- phase 1: all B frags + A quadrant 0 ---- */                      \
    af0 = *(const short8*)(Lb + rA + pm0);                                   \
    af1 = *(const short8*)(Lb + rA + pm1);                                   \
    af2 = *(const short8*)(Lb + rA + 1024 + pm0);                            \
    af3 = *(const short8*)(Lb + rA + 1024 + pm1);                            \
    bf[0][0] = *(const short8*)(Lb + rB + pm0);                              \
    bf[0][1] = *(const short8*)(Lb + rB + pm1);                              \
    bf[1][0] = *(const short8*)(Lb + rB + 1024 + pm0);                       \
    bf[1][1] = *(const short8*)(Lb + rB + 1024 + pm1);                       \
    bf[2][0] = *(const short8*)(Lb + rB + 2048 + pm0);                       \
    bf[2][1] = *(const short8*)(Lb + rB + 2048 + pm1);                       \
    bf[3][0] = *(const short8*)(Lb + rB + 3072 + pm0);                       \
    bf[3][1] = *(const short8*)(Lb + rB + 3072 + pm1);                       \
    if (S1) {                                                                \
        gload16(Sb + 24576 + t8, A + offA1 + kadv1);                         \
        gload16(Sb + 28672 + t8, A + offA1 + 32 * K_DIM + kadv1);            \
    }                                                                        \
    BAR();                                                                   \
    KPH_MFMA(0);                                                             \
    BAR();                                                                   \
    /* ---- phase 2: A quadrant 1 ---- */                                    \
    af0 = *(const short8*)(Lb + rA + 4096 + pm0);                            \
    af1 = *(const short8*)(Lb + rA + 4096 + pm1);                            \
    af2 = *(const short8*)(Lb + rA + 5120 + pm0);                            \
    af3 = *(const short8*)(Lb + rA + 5120 + pm1);                            \
    if (S2) {                                                                \
        gload16(Cb + t8, B + offB0 + kadv2);                                 \
        gload16(Cb + 4096 + t8, B + offB0 + 64 * K_DIM + kadv2);             \
    }                                                                        \
    BAR();                                                                   \
    KPH_MFMA(1);                                                             \
    BAR();                                                                   \
    /* ---- phase 3: A quadrant 2 ---- */                                    \
    af0 = *(const short8*)(Lb + rA + 8192 + pm0);                            \
    af1 = *(const short8*)(Lb + rA + 8192 + pm1);                            \
    af2 = *(const short8*)(Lb + rA + 9216 + pm0);                            \
    af3 = *(const short8*)(Lb + rA + 9216 + pm1);                            \
    if (S2) {                                                                \
        gload16(Cb + 8192 + t8, B + offB1 + kadv2);                          \
        gload16(Cb + 12288 + t8, B + offB1 + 64 * K_DIM + kadv2);            \
    }                                                                        \
    BAR();                                                                   \
    KPH_MFMA(2);                                                             \
    BAR();                                                                   \
    /* ---- phase 4: A quadrant 3, counted vmcnt ---- */                     \
    af0 = *(const short8*)(Lb + rA + 12288 + pm0);                           \
    af1 = *(const short8*)(Lb + rA + 12288 + pm1);                           \
    af2 = *(const short8*)(Lb + rA + 13312 + pm0);                           \
    af3 = *(const short8*)(Lb + rA + 13312 + pm1);                           \
    if (S2) {                                                                \
        gload16(Cb + 16384 + t8, A + offA0 + kadv2);                         \
        gload16(Cb + 20480 + t8, A + offA0 + 32 * K_DIM + kadv2);            \
    }                                                                        \
    VMCNT(VMN);                                                              \
    BAR();                                                                   \
    KPH_MFMA(3);                                                             \
    BAR();                                                                   \
  }

__global__ __launch_bounds__(512, 2) void gemm_8ph(const u16* __restrict__ A,
                                                   const u16* __restrict__ B,
                                                   const float* __restrict__ scale,
                                                   const float* __restrict__ bias,
                                                   float* __restrict__ C) {
    extern __shared__ u16 lds[];   // 2 x 32768 u16 = 128 KiB

    const int t   = threadIdx.x;
    const int bid = blockIdx.x;
    // Bijective XCD swizzle: 2048 blocks, 2048 % 8 == 0.
    const int swz = (bid & 7) * 256 + (bid >> 3);
    const int n0  = (swz & 63) * 256;
    const int m0  = (swz >> 6) * 256;

    // ---- staging addressing (per-thread, linear LDS dest = t*16 B) ----
    const int t8    = t * 8;
    const int ksrc8 = ((t & 7) ^ ((t >> 3) & 7)) * 8;  // pre-swizzled source k-chunk
    const int offB0 = (n0 + (t >> 3)) * K_DIM + ksrc8;                 // B-h0, j=0
    const int offB1 = offB0 + 128 * K_DIM;                             // B-h1, j=0
    const int offA0 = (m0 + ((t >> 8) & 1) * 128 + ((t >> 3) & 31)) * K_DIM
                      + ksrc8;                                         // A-q01, j=0 (q=0)
    const int offA1 = offA0 + 64 * K_DIM;                              // A-q23, j=0 (q=2)

    // ---- fragment addressing ----
    const int wid = t >> 6, l = t & 63;
    const int mg = wid >> 2, ng = wid & 3;   // wave grid 2(M) x 4(N)
    const int ql = l >> 4, r = l & 15;
    const int pm0 = (ql ^ (r & 7)) * 8;          // swizzled chunk, kslice 0
    const int pm1 = ((4 + ql) ^ (r & 7)) * 8;    // swizzled chunk, kslice 1
    const int rB = (ng * 64 + r) * 64;
    const int rA = 16384 + (mg * 32 + r) * 64;

    floatx4 acc[8][4] = {};
    short8 bf[4][2];
    short8 af0, af1, af2, af3;

    // ---- prologue: tile0 fully + tile1 {B-h0,B-h1,A-q01}; leave 6 in flight
    {
        u16* b0 = lds;
        u16* b1 = lds + 32768;
        gload16(b0 +     0 + t8, B + offB0);
        gload16(b0 +  4096 + t8, B + offB0 + 64 * K_DIM);
        gload16(b0 +  8192 + t8, B + offB1);
        gload16(b0 + 12288 + t8, B + offB1 + 64 * K_DIM);
        gload16(b0 + 16384 + t8, A + offA0);
        gload16(b0 + 20480 + t8, A + offA0 + 32 * K_DIM);
        gload16(b0 + 24576 + t8, A + offA1);
        gload16(b0 + 28672 + t8, A + offA1 + 32 * K_DIM);
        gload16(b1 +     0 + t8, B + offB0 + 64);
        gload16(b1 +  4096 + t8, B + offB0 + 64 * K_DIM + 64);
        gload16(b1 +  8192 + t8, B + offB1 + 64);
        gload16(b1 + 12288 + t8, B + offB1 + 64 * K_DIM + 64);
        gload16(b1 + 16384 + t8, A + offA0 + 64);
        gload16(b1 + 20480 + t8, A + offA0 + 32 * K_DIM + 64);
        VMCNT(6);   // tile0 resident; tile1's 3 pieces still in flight
        BAR();
    }

    int cur = 0;
    int kt = 0;
    for (; kt < 62; ++kt) {       // steady state
        KTILE(1, 1, 6);
        cur ^= 1;
    }
    KTILE(1, 0, 0);               // kt == 62: only A-q23(63); drain
    cur ^= 1; ++kt;
    KTILE(0, 0, 0);               // kt == 63: no staging

    // ---- epilogue: C/D layout col = lane&15, row = quad*4 + reg ----
#pragma unroll
    for (int j = 0; j < 4; ++j) {
        const int cn  = n0 + ng * 64 + j * 16 + r;
        const float sc = scale[cn];
        const float bi = bias[cn];
#pragma unroll
        for (int i = 0; i < 8; ++i) {
            const int cm = m0 + mg * 128 + i * 16 + ql * 4;
            float* crow = C + (size_t)cm * N_DIM + cn;
#pragma unroll
            for (int v = 0; v < 4; ++v)
                crow[(size_t)v * N_DIM] = acc[i][j][v] * sc + bi;
        }
    }
}

// ---------------------------------------------------------------------------
// Launch: ws = [ xb: 64 MiB bf16 x | wt: 128 MiB bf16 Wt ] (unchanged).
// ---------------------------------------------------------------------------
extern "C" void kernel_launch(void* const* d_in, const int* in_sizes, int n_in,
                              void* d_out, int out_size, void* d_ws, size_t ws_size,
                              hipStream_t stream) {
    const float* x     = (const float*)d_in[0];
    const int*   wq    = (const int*)d_in[1];
    const float* scale = (const float*)d_in[2];
    const float* bias  = (const float*)d_in[3];
    float*       out   = (float*)d_out;

    u16* xb = (u16*)d_ws;
    u16* wt = (u16*)((char*)d_ws + (size_t)M_DIM * K_DIM * 2);

    static int attr_done = 0;
    if (!attr_done) {   // host-side, capture-safe, once: allow 128 KiB dynamic LDS
        (void)hipFuncSetAttribute((const void*)gemm_8ph,
                                  hipFuncAttributeMaxDynamicSharedMemorySize, 131072);
        attr_done = 1;
    }

    cvt_x_bf16<<<dim3((M_DIM * K_DIM) / (256 * 8)), dim3(256), 0, stream>>>(x, xb);
    cvt_w_t<<<dim3(N_DIM / 64, K_DIM / 256), dim3(256), 0, stream>>>(wq, wt);
    gemm_8ph<<<dim3((M_DIM / 256) * (N_DIM / 256)), dim3(512), 131072, stream>>>(
        xb, wt, scale, bias, out);
}